// Round 2
// baseline (2933.788 us; speedup 1.0000x reference)
//
#include <hip/hip_runtime.h>

// Fused self-attention block baseline (fp32, vector ALU).
//   B=8, S=2048, D=1024
//   Q = x@Wq^T + bq ; K = x@Wk^T + bk ; V = x@Wv^T + bv
//   P = softmax(Q K^T / 32) ; out = P V + x ; LayerNorm(out)
// Decomposition: gemm_nt (C = alpha*A*B^T + bias) for QKV and scores,
// row softmax, gemm_nn_resid (C = A*B + R) for PV+residual, wave-per-row LN.
// Q lives in d_out (overwritten by PV only after consumption, stream-ordered).
// ws: K (64MB) + V (64MB) + scores (128MB batched / 16MB per-batch fallback).

#define TB 256

// C[m][n] = alpha * sum_k A[m][k]*B[n][k]  (+ bias[n])
// 128x128 tile, BK=16, 8x8 per thread, register prefetch.
__global__ __launch_bounds__(TB) void gemm_nt(
    const float* __restrict__ A, const float* __restrict__ B,
    float* __restrict__ C, const float* __restrict__ bias, float alpha,
    int M, int N, int K, int lda, int ldb, int ldc,
    size_t sA, size_t sB, size_t sC)
{
  A += (size_t)blockIdx.z * sA;
  B += (size_t)blockIdx.z * sB;
  C += (size_t)blockIdx.z * sC;
  __shared__ __align__(16) float As[16][132];
  __shared__ __align__(16) float Bs[16][132];
  const int t = threadIdx.x;
  const int tx = t & 15, ty = t >> 4;
  const int gm0 = blockIdx.y * 128, gn0 = blockIdx.x * 128;

  float acc[8][8];
#pragma unroll
  for (int i = 0; i < 8; ++i)
#pragma unroll
    for (int j = 0; j < 8; ++j) acc[i][j] = 0.f;

  const int nk = K >> 4;
  float4 pa[2], pb[2];
#pragma unroll
  for (int h = 0; h < 2; ++h) {
    const int i = t + h * 256, r = i >> 2, c4 = (i & 3) << 2;
    pa[h] = *(const float4*)&A[(size_t)(gm0 + r) * lda + c4];
    pb[h] = *(const float4*)&B[(size_t)(gn0 + r) * ldb + c4];
  }
  for (int kt = 0; kt < nk; ++kt) {
    __syncthreads();
#pragma unroll
    for (int h = 0; h < 2; ++h) {
      const int i = t + h * 256, r = i >> 2, c4 = (i & 3) << 2;
      As[c4 + 0][r] = pa[h].x; As[c4 + 1][r] = pa[h].y;
      As[c4 + 2][r] = pa[h].z; As[c4 + 3][r] = pa[h].w;
      Bs[c4 + 0][r] = pb[h].x; Bs[c4 + 1][r] = pb[h].y;
      Bs[c4 + 2][r] = pb[h].z; Bs[c4 + 3][r] = pb[h].w;
    }
    __syncthreads();
    if (kt + 1 < nk) {
      const int k0 = (kt + 1) << 4;
#pragma unroll
      for (int h = 0; h < 2; ++h) {
        const int i = t + h * 256, r = i >> 2, c4 = (i & 3) << 2;
        pa[h] = *(const float4*)&A[(size_t)(gm0 + r) * lda + k0 + c4];
        pb[h] = *(const float4*)&B[(size_t)(gn0 + r) * ldb + k0 + c4];
      }
    }
#pragma unroll
    for (int k = 0; k < 16; ++k) {
      const float4 a0 = *(const float4*)&As[k][ty * 8];
      const float4 a1 = *(const float4*)&As[k][ty * 8 + 4];
      const float4 b0 = *(const float4*)&Bs[k][tx * 8];
      const float4 b1 = *(const float4*)&Bs[k][tx * 8 + 4];
      const float av[8] = {a0.x, a0.y, a0.z, a0.w, a1.x, a1.y, a1.z, a1.w};
      const float bv[8] = {b0.x, b0.y, b0.z, b0.w, b1.x, b1.y, b1.z, b1.w};
#pragma unroll
      for (int i = 0; i < 8; ++i)
#pragma unroll
        for (int j = 0; j < 8; ++j) acc[i][j] += av[i] * bv[j];
    }
  }
  float4 bb0 = make_float4(0.f, 0.f, 0.f, 0.f), bb1 = bb0;
  if (bias) {
    bb0 = *(const float4*)&bias[gn0 + tx * 8];
    bb1 = *(const float4*)&bias[gn0 + tx * 8 + 4];
  }
#pragma unroll
  for (int i = 0; i < 8; ++i) {
    const size_t off = (size_t)(gm0 + ty * 8 + i) * ldc + gn0 + tx * 8;
    float4 c0, c1;
    c0.x = acc[i][0] * alpha + bb0.x; c0.y = acc[i][1] * alpha + bb0.y;
    c0.z = acc[i][2] * alpha + bb0.z; c0.w = acc[i][3] * alpha + bb0.w;
    c1.x = acc[i][4] * alpha + bb1.x; c1.y = acc[i][5] * alpha + bb1.y;
    c1.z = acc[i][6] * alpha + bb1.z; c1.w = acc[i][7] * alpha + bb1.w;
    *(float4*)&C[off] = c0;
    *(float4*)&C[off + 4] = c1;
  }
}

// C[m][n] = sum_k A[m][k]*B[k][n] + R[m][n]   (R and C share ldc)
__global__ __launch_bounds__(TB) void gemm_nn_resid(
    const float* __restrict__ A, const float* __restrict__ B,
    const float* __restrict__ R, float* __restrict__ C,
    int M, int N, int K, int lda, int ldb, int ldc,
    size_t sA, size_t sB, size_t sR, size_t sC)
{
  A += (size_t)blockIdx.z * sA;
  B += (size_t)blockIdx.z * sB;
  R += (size_t)blockIdx.z * sR;
  C += (size_t)blockIdx.z * sC;
  __shared__ __align__(16) float As[16][132];
  __shared__ __align__(16) float Bs[16][132];
  const int t = threadIdx.x;
  const int tx = t & 15, ty = t >> 4;
  const int gm0 = blockIdx.y * 128, gn0 = blockIdx.x * 128;

  float acc[8][8];
#pragma unroll
  for (int i = 0; i < 8; ++i)
#pragma unroll
    for (int j = 0; j < 8; ++j) acc[i][j] = 0.f;

  const int nk = K >> 4;
  float4 pa[2], pb[2];
#pragma unroll
  for (int h = 0; h < 2; ++h) {
    const int i = t + h * 256;
    const int ra = i >> 2, ca = (i & 3) << 2;
    const int rb = i >> 5, cb = (i & 31) << 2;
    pa[h] = *(const float4*)&A[(size_t)(gm0 + ra) * lda + ca];
    pb[h] = *(const float4*)&B[(size_t)rb * ldb + gn0 + cb];
  }
  for (int kt = 0; kt < nk; ++kt) {
    __syncthreads();
#pragma unroll
    for (int h = 0; h < 2; ++h) {
      const int i = t + h * 256;
      const int ra = i >> 2, ca = (i & 3) << 2;
      const int rb = i >> 5, cb = (i & 31) << 2;
      As[ca + 0][ra] = pa[h].x; As[ca + 1][ra] = pa[h].y;
      As[ca + 2][ra] = pa[h].z; As[ca + 3][ra] = pa[h].w;
      *(float4*)&Bs[rb][cb] = pb[h];
    }
    __syncthreads();
    if (kt + 1 < nk) {
      const int k0 = (kt + 1) << 4;
#pragma unroll
      for (int h = 0; h < 2; ++h) {
        const int i = t + h * 256;
        const int ra = i >> 2, ca = (i & 3) << 2;
        const int rb = i >> 5, cb = (i & 31) << 2;
        pa[h] = *(const float4*)&A[(size_t)(gm0 + ra) * lda + k0 + ca];
        pb[h] = *(const float4*)&B[(size_t)(k0 + rb) * ldb + gn0 + cb];
      }
    }
#pragma unroll
    for (int k = 0; k < 16; ++k) {
      const float4 a0 = *(const float4*)&As[k][ty * 8];
      const float4 a1 = *(const float4*)&As[k][ty * 8 + 4];
      const float4 b0 = *(const float4*)&Bs[k][tx * 8];
      const float4 b1 = *(const float4*)&Bs[k][tx * 8 + 4];
      const float av[8] = {a0.x, a0.y, a0.z, a0.w, a1.x, a1.y, a1.z, a1.w};
      const float bv[8] = {b0.x, b0.y, b0.z, b0.w, b1.x, b1.y, b1.z, b1.w};
#pragma unroll
      for (int i = 0; i < 8; ++i)
#pragma unroll
        for (int j = 0; j < 8; ++j) acc[i][j] += av[i] * bv[j];
    }
  }
#pragma unroll
  for (int i = 0; i < 8; ++i) {
    const size_t off = (size_t)(gm0 + ty * 8 + i) * ldc + gn0 + tx * 8;
    const float4 r0 = *(const float4*)&R[off];
    const float4 r1 = *(const float4*)&R[off + 4];
    float4 c0, c1;
    c0.x = acc[i][0] + r0.x; c0.y = acc[i][1] + r0.y;
    c0.z = acc[i][2] + r0.z; c0.w = acc[i][3] + r0.w;
    c1.x = acc[i][4] + r1.x; c1.y = acc[i][5] + r1.y;
    c1.z = acc[i][6] + r1.z; c1.w = acc[i][7] + r1.w;
    *(float4*)&C[off] = c0;
    *(float4*)&C[off + 4] = c1;
  }
}

// In-place row softmax, row length 2048, one 256-thread block per row.
__global__ __launch_bounds__(TB) void softmax2048(float* __restrict__ S)
{
  __shared__ float redm[4];
  __shared__ float reds[4];
  const int t = threadIdx.x;
  float* p = S + (size_t)blockIdx.x * 2048;
  float4 a = *(const float4*)&p[t * 4];
  float4 b = *(const float4*)&p[t * 4 + 1024];
  float m = fmaxf(fmaxf(fmaxf(a.x, a.y), fmaxf(a.z, a.w)),
                  fmaxf(fmaxf(b.x, b.y), fmaxf(b.z, b.w)));
#pragma unroll
  for (int o = 32; o; o >>= 1) m = fmaxf(m, __shfl_xor(m, o));
  if ((t & 63) == 0) redm[t >> 6] = m;
  __syncthreads();
  m = fmaxf(fmaxf(redm[0], redm[1]), fmaxf(redm[2], redm[3]));
  a.x = __expf(a.x - m); a.y = __expf(a.y - m);
  a.z = __expf(a.z - m); a.w = __expf(a.w - m);
  b.x = __expf(b.x - m); b.y = __expf(b.y - m);
  b.z = __expf(b.z - m); b.w = __expf(b.w - m);
  float s = a.x + a.y + a.z + a.w + b.x + b.y + b.z + b.w;
#pragma unroll
  for (int o = 32; o; o >>= 1) s += __shfl_xor(s, o);
  if ((t & 63) == 0) reds[t >> 6] = s;
  __syncthreads();
  s = reds[0] + reds[1] + reds[2] + reds[3];
  const float inv = 1.0f / s;
  a.x *= inv; a.y *= inv; a.z *= inv; a.w *= inv;
  b.x *= inv; b.y *= inv; b.z *= inv; b.w *= inv;
  *(float4*)&p[t * 4] = a;
  *(float4*)&p[t * 4 + 1024] = b;
}

// In-place LayerNorm over D=1024, one wave per row.
__global__ __launch_bounds__(64) void ln1024(
    float* __restrict__ O, const float* __restrict__ g, const float* __restrict__ be)
{
  const int l = threadIdx.x;
  float* p = O + (size_t)blockIdx.x * 1024;
  float4 v[4];
#pragma unroll
  for (int i = 0; i < 4; ++i) v[i] = *(const float4*)&p[l * 4 + i * 256];
  float s = 0.f, q = 0.f;
#pragma unroll
  for (int i = 0; i < 4; ++i) {
    s += v[i].x + v[i].y + v[i].z + v[i].w;
    q += v[i].x * v[i].x + v[i].y * v[i].y + v[i].z * v[i].z + v[i].w * v[i].w;
  }
#pragma unroll
  for (int o = 32; o; o >>= 1) { s += __shfl_xor(s, o); q += __shfl_xor(q, o); }
  const float mu = s * (1.0f / 1024.0f);
  const float var = q * (1.0f / 1024.0f) - mu * mu;
  const float rs = rsqrtf(var + 1e-5f);
#pragma unroll
  for (int i = 0; i < 4; ++i) {
    const float4 gg = *(const float4*)&g[l * 4 + i * 256];
    const float4 bb = *(const float4*)&be[l * 4 + i * 256];
    float4 o4;
    o4.x = (v[i].x - mu) * rs * gg.x + bb.x;
    o4.y = (v[i].y - mu) * rs * gg.y + bb.y;
    o4.z = (v[i].z - mu) * rs * gg.z + bb.z;
    o4.w = (v[i].w - mu) * rs * gg.w + bb.w;
    *(float4*)&p[l * 4 + i * 256] = o4;
  }
}

extern "C" void kernel_launch(void* const* d_in, const int* in_sizes, int n_in,
                              void* d_out, int out_size, void* d_ws, size_t ws_size,
                              hipStream_t stream) {
  (void)in_sizes; (void)n_in; (void)out_size;
  constexpr int Bb = 8, S = 2048, D = 1024;
  const size_t BS = (size_t)Bb * S;  // 16384 rows

  const float* x     = (const float*)d_in[0];
  const float* Wq    = (const float*)d_in[1];
  const float* bq    = (const float*)d_in[2];
  const float* Wk    = (const float*)d_in[3];
  const float* bk    = (const float*)d_in[4];
  const float* Wv    = (const float*)d_in[5];
  const float* bv    = (const float*)d_in[6];
  const float* gamma = (const float*)d_in[7];
  const float* beta  = (const float*)d_in[8];
  float* out = (float*)d_out;

  float* Kbuf = (float*)d_ws;
  float* Vbuf = Kbuf + BS * (size_t)D;
  float* Sbuf = Vbuf + BS * (size_t)D;

  const dim3 blk(TB);
  const float sc = 0.03125f;  // 1/sqrt(1024)

  // QKV projections: Q -> d_out, K/V -> ws
  gemm_nt<<<dim3(D / 128, (int)(BS / 128), 1), blk, 0, stream>>>(
      x, Wq, out, bq, 1.0f, (int)BS, D, D, D, D, D, 0, 0, 0);
  gemm_nt<<<dim3(D / 128, (int)(BS / 128), 1), blk, 0, stream>>>(
      x, Wk, Kbuf, bk, 1.0f, (int)BS, D, D, D, D, D, 0, 0, 0);
  gemm_nt<<<dim3(D / 128, (int)(BS / 128), 1), blk, 0, stream>>>(
      x, Wv, Vbuf, bv, 1.0f, (int)BS, D, D, D, D, D, 0, 0, 0);

  const size_t needBatched =
      (BS * (size_t)D * 2 + (size_t)Bb * S * (size_t)S) * sizeof(float);  // ~256MB
  if (ws_size >= needBatched) {
    // Batched attention over all 8 batches (full grid parallelism)
    gemm_nt<<<dim3(S / 128, S / 128, Bb), blk, 0, stream>>>(
        out, Kbuf, Sbuf, nullptr, sc, S, S, D, D, D, S,
        (size_t)S * D, (size_t)S * D, (size_t)S * S);
    softmax2048<<<dim3((int)BS), blk, 0, stream>>>(Sbuf);
    gemm_nn_resid<<<dim3(D / 128, S / 128, Bb), blk, 0, stream>>>(
        Sbuf, Vbuf, x, out, S, D, S, S, D, D,
        (size_t)S * S, (size_t)S * D, (size_t)S * D, (size_t)S * D);
  } else {
    // Per-batch fallback: scores buffer reused (16MB), needs ~151MB ws
    for (int b = 0; b < Bb; ++b) {
      const size_t o = (size_t)b * S * D;
      gemm_nt<<<dim3(S / 128, S / 128, 1), blk, 0, stream>>>(
          out + o, Kbuf + o, Sbuf, nullptr, sc, S, S, D, D, D, S, 0, 0, 0);
      softmax2048<<<dim3(S), blk, 0, stream>>>(Sbuf);
      gemm_nn_resid<<<dim3(D / 128, S / 128, 1), blk, 0, stream>>>(
          Sbuf, Vbuf + o, x + o, out + o, S, D, S, S, D, D, 0, 0, 0, 0);
    }
  }
  ln1024<<<dim3((int)BS), dim3(64), 0, stream>>>(out, gamma, beta);
}

// Round 3
// 613.946 us; speedup vs baseline: 4.7786x; 4.7786x over previous
//
#include <hip/hip_runtime.h>

// Self-attention block, bf16-MFMA version.
//   B=8, S=2048, D=1024
// Pipeline: f32->bf16 converts; Q,K projections (bf16 out); V projection
// (bf16 out, TRANSPOSED -> Vt[n][m]); scores = Q K^T /32 (fp32 out);
// softmax (fp32 in, bf16 P in-place); PV^T NT-GEMM + residual (fp32 out); LN.
// GEMM: 128x128 tile, BK=32, 4 waves (2x2), 4x4 16x16x32 MFMA frags/wave,
// global_load_lds width-16 staging, linear LDS, 2-barrier K-loop (m97 style).
// ws layout (exactly 268,435,456 B): xb|Qb|Kb|Vt bf16 (134MB) + Sbuf f32
// (128MB). W bf16 copies live in the head of Sbuf (dead before scores write).

typedef __bf16 bf16x8 __attribute__((ext_vector_type(8)));
typedef float f32x4 __attribute__((ext_vector_type(4)));

#define BM 128
#define BN 128
#define BK 32

enum { M_QK = 0, M_VT = 1, M_SC = 2, M_PV = 3 };

__device__ __forceinline__ unsigned short f2b(float f) {
  union { float f; unsigned int u; } v; v.f = f;
  return (unsigned short)((v.u + 0x7FFFu + ((v.u >> 16) & 1u)) >> 16);
}

__device__ __forceinline__ void gload_lds16(const void* g, void* l) {
  __builtin_amdgcn_global_load_lds(
      (const __attribute__((address_space(1))) void*)g,
      (__attribute__((address_space(3))) void*)l, 16, 0, 0);
}

// C = A * B^T (both A,B row-major [rows][K] bf16), fp32 accum.
// MODE epilogues: QK: bf16 C + bias; VT: bf16 C transposed + bias (per-batch);
// SC: f32 C * alpha; PV: f32 C + residual.
template <int MODE>
__global__ __launch_bounds__(256) void gemm_bf16(
    const unsigned short* __restrict__ A, const unsigned short* __restrict__ B,
    void* __restrict__ Cv, const float* __restrict__ aux, float alpha,
    int K, int ldaE, int ldbE, int ldcE,
    size_t sA, size_t sB, size_t sC, size_t sR)
{
  const int t = threadIdx.x, l = t & 63, w = t >> 6;
  const int wm = w >> 1, wn = w & 1;
  const int bz = blockIdx.z;
  A += (size_t)bz * sA;
  B += (size_t)bz * sB;
  const int gm0 = blockIdx.y * BM, gn0 = blockIdx.x * BN;

  __shared__ __align__(16) unsigned short As[BM * BK];
  __shared__ __align__(16) unsigned short Bs[BN * BK];

  f32x4 acc[4][4];
#pragma unroll
  for (int i = 0; i < 4; ++i)
#pragma unroll
    for (int j = 0; j < 4; ++j) acc[i][j] = f32x4{0.f, 0.f, 0.f, 0.f};

  const int srow = w * 16 + (l >> 2);      // staging row within 64-row chunk base
  const int scolb = (l & 3) << 4;          // staging byte col (0..48)
  const int rr = l & 15;                   // fragment row/col within 16
  const int k0 = (l >> 4) << 3;            // fragment k chunk (0 or 8..24)

  for (int kt = 0; kt < K; kt += BK) {
    __syncthreads();
#pragma unroll
    for (int c = 0; c < 2; ++c) {
      const int r = c * 64 + srow;
      gload_lds16((const char*)(A + (size_t)(gm0 + r) * ldaE + kt) + scolb,
                  (char*)As + c * 4096 + w * 1024);
      gload_lds16((const char*)(B + (size_t)(gn0 + r) * ldbE + kt) + scolb,
                  (char*)Bs + c * 4096 + w * 1024);
    }
    __syncthreads();
    bf16x8 av[4], bv[4];
#pragma unroll
    for (int i = 0; i < 4; ++i)
      av[i] = *(const bf16x8*)&As[(wm * 64 + i * 16 + rr) * BK + k0];
#pragma unroll
    for (int j = 0; j < 4; ++j)
      bv[j] = *(const bf16x8*)&Bs[(wn * 64 + j * 16 + rr) * BK + k0];
#pragma unroll
    for (int i = 0; i < 4; ++i)
#pragma unroll
      for (int j = 0; j < 4; ++j)
        acc[i][j] = __builtin_amdgcn_mfma_f32_16x16x32_bf16(av[i], bv[j], acc[i][j], 0, 0, 0);
  }

  // Epilogue. Frag (i,j): rows gm0+wm*64+i*16+(l>>4)*4+r, col gn0+wn*64+j*16+(l&15).
  const int col_l = l & 15, row0_l = (l >> 4) << 2;
#pragma unroll
  for (int i = 0; i < 4; ++i) {
    const int gr = gm0 + wm * 64 + i * 16 + row0_l;
#pragma unroll
    for (int j = 0; j < 4; ++j) {
      const int gc = gn0 + wn * 64 + j * 16 + col_l;
      if constexpr (MODE == M_QK) {
        unsigned short* C = (unsigned short*)Cv;
        const float b = aux[gc];
#pragma unroll
        for (int r = 0; r < 4; ++r)
          C[(size_t)(gr + r) * ldcE + gc] = f2b(acc[i][j][r] + b);
      } else if constexpr (MODE == M_VT) {
        unsigned short* C = (unsigned short*)Cv;
        const float b = aux[gc];
        const int bat = gr >> 11, lm = gr & 2047;
        ushort4 o = make_ushort4(f2b(acc[i][j][0] + b), f2b(acc[i][j][1] + b),
                                 f2b(acc[i][j][2] + b), f2b(acc[i][j][3] + b));
        *(ushort4*)&C[(size_t)bat * sC + (size_t)gc * ldcE + lm] = o;
      } else if constexpr (MODE == M_SC) {
        float* C = (float*)Cv + (size_t)bz * sC;
        float* p = C + (size_t)gr * ldcE + gc;
#pragma unroll
        for (int r = 0; r < 4; ++r) p[(size_t)r * ldcE] = acc[i][j][r] * alpha;
      } else {  // M_PV
        float* C = (float*)Cv + (size_t)bz * sC;
        const float* R = aux + (size_t)bz * sR;
        float* p = C + (size_t)gr * ldcE + gc;
        const float* q = R + (size_t)gr * ldcE + gc;
#pragma unroll
        for (int r = 0; r < 4; ++r) p[(size_t)r * ldcE] = acc[i][j][r] + q[(size_t)r * ldcE];
      }
    }
  }
}

__global__ __launch_bounds__(256) void f32_to_bf16(
    const float* __restrict__ s, unsigned short* __restrict__ d)
{
  const size_t i = (size_t)blockIdx.x * 256 + threadIdx.x;
  const float4 a = ((const float4*)s)[i * 2];
  const float4 b = ((const float4*)s)[i * 2 + 1];
  ((ushort4*)d)[i * 2]     = make_ushort4(f2b(a.x), f2b(a.y), f2b(a.z), f2b(a.w));
  ((ushort4*)d)[i * 2 + 1] = make_ushort4(f2b(b.x), f2b(b.y), f2b(b.z), f2b(b.w));
}

// Row softmax, fp32 in (row of 2048), bf16 out written in-place at row head.
__global__ __launch_bounds__(256) void softmax2048_bf16(float* __restrict__ S)
{
  __shared__ float redm[4];
  __shared__ float reds[4];
  const int t = threadIdx.x;
  float* p = S + (size_t)blockIdx.x * 2048;
  float4 a = *(const float4*)&p[t * 4];
  float4 b = *(const float4*)&p[t * 4 + 1024];
  float m = fmaxf(fmaxf(fmaxf(a.x, a.y), fmaxf(a.z, a.w)),
                  fmaxf(fmaxf(b.x, b.y), fmaxf(b.z, b.w)));
#pragma unroll
  for (int o = 32; o; o >>= 1) m = fmaxf(m, __shfl_xor(m, o));
  if ((t & 63) == 0) redm[t >> 6] = m;
  __syncthreads();
  m = fmaxf(fmaxf(redm[0], redm[1]), fmaxf(redm[2], redm[3]));
  a.x = __expf(a.x - m); a.y = __expf(a.y - m);
  a.z = __expf(a.z - m); a.w = __expf(a.w - m);
  b.x = __expf(b.x - m); b.y = __expf(b.y - m);
  b.z = __expf(b.z - m); b.w = __expf(b.w - m);
  float s = a.x + a.y + a.z + a.w + b.x + b.y + b.z + b.w;
#pragma unroll
  for (int o = 32; o; o >>= 1) s += __shfl_xor(s, o);
  if ((t & 63) == 0) reds[t >> 6] = s;
  __syncthreads();
  s = reds[0] + reds[1] + reds[2] + reds[3];
  const float inv = 1.0f / s;
  unsigned short* pb = (unsigned short*)p;
  *(ushort4*)&pb[t * 4] =
      make_ushort4(f2b(a.x * inv), f2b(a.y * inv), f2b(a.z * inv), f2b(a.w * inv));
  *(ushort4*)&pb[1024 + t * 4] =
      make_ushort4(f2b(b.x * inv), f2b(b.y * inv), f2b(b.z * inv), f2b(b.w * inv));
}

// In-place LayerNorm over D=1024, one wave per row.
__global__ __launch_bounds__(64) void ln1024(
    float* __restrict__ O, const float* __restrict__ g, const float* __restrict__ be)
{
  const int l = threadIdx.x;
  float* p = O + (size_t)blockIdx.x * 1024;
  float4 v[4];
#pragma unroll
  for (int i = 0; i < 4; ++i) v[i] = *(const float4*)&p[l * 4 + i * 256];
  float s = 0.f, q = 0.f;
#pragma unroll
  for (int i = 0; i < 4; ++i) {
    s += v[i].x + v[i].y + v[i].z + v[i].w;
    q += v[i].x * v[i].x + v[i].y * v[i].y + v[i].z * v[i].z + v[i].w * v[i].w;
  }
#pragma unroll
  for (int o = 32; o; o >>= 1) { s += __shfl_xor(s, o); q += __shfl_xor(q, o); }
  const float mu = s * (1.0f / 1024.0f);
  const float var = q * (1.0f / 1024.0f) - mu * mu;
  const float rs = rsqrtf(var + 1e-5f);
#pragma unroll
  for (int i = 0; i < 4; ++i) {
    const float4 gg = *(const float4*)&g[l * 4 + i * 256];
    const float4 bb = *(const float4*)&be[l * 4 + i * 256];
    float4 o4;
    o4.x = (v[i].x - mu) * rs * gg.x + bb.x;
    o4.y = (v[i].y - mu) * rs * gg.y + bb.y;
    o4.z = (v[i].z - mu) * rs * gg.z + bb.z;
    o4.w = (v[i].w - mu) * rs * gg.w + bb.w;
    *(float4*)&p[l * 4 + i * 256] = o4;
  }
}

extern "C" void kernel_launch(void* const* d_in, const int* in_sizes, int n_in,
                              void* d_out, int out_size, void* d_ws, size_t ws_size,
                              hipStream_t stream) {
  (void)in_sizes; (void)n_in; (void)out_size; (void)ws_size;
  constexpr int Bb = 8, S = 2048, D = 1024;
  const size_t BS = (size_t)Bb * S;           // 16384 rows
  const size_t ND = BS * (size_t)D;           // 16,777,216 elements

  const float* x     = (const float*)d_in[0];
  const float* Wq    = (const float*)d_in[1];
  const float* bq    = (const float*)d_in[2];
  const float* Wk    = (const float*)d_in[3];
  const float* bk    = (const float*)d_in[4];
  const float* Wv    = (const float*)d_in[5];
  const float* bv    = (const float*)d_in[6];
  const float* gamma = (const float*)d_in[7];
  const float* beta  = (const float*)d_in[8];
  float* out = (float*)d_out;

  // ws: xb | Qb | Kb | Vt (bf16) | Sbuf (f32). W bf16 copies in Sbuf head.
  unsigned short* xb = (unsigned short*)d_ws;
  unsigned short* Qb = xb + ND;
  unsigned short* Kb = Qb + ND;
  unsigned short* Vt = Kb + ND;
  float* Sbuf = (float*)(Vt + ND);
  unsigned short* Wqb = (unsigned short*)Sbuf;
  unsigned short* Wkb = Wqb + (size_t)D * D;
  unsigned short* Wvb = Wkb + (size_t)D * D;

  // Converts (exact grids: n/8/256 blocks)
  f32_to_bf16<<<dim3(8192), dim3(256), 0, stream>>>(x, xb);
  f32_to_bf16<<<dim3(512), dim3(256), 0, stream>>>(Wq, Wqb);
  f32_to_bf16<<<dim3(512), dim3(256), 0, stream>>>(Wk, Wkb);
  f32_to_bf16<<<dim3(512), dim3(256), 0, stream>>>(Wv, Wvb);

  const dim3 blk(256);
  // Projections: M=BS(16384), N=D, K=D
  const dim3 g1(D / BN, (int)(BS / BM), 1);
  gemm_bf16<M_QK><<<g1, blk, 0, stream>>>(xb, Wqb, Qb, bq, 1.f, D, D, D, D, 0, 0, 0, 0);
  gemm_bf16<M_QK><<<g1, blk, 0, stream>>>(xb, Wkb, Kb, bk, 1.f, D, D, D, D, 0, 0, 0, 0);
  gemm_bf16<M_VT><<<g1, blk, 0, stream>>>(xb, Wvb, Vt, bv, 1.f, D, D, D, S, 0, 0,
                                          (size_t)D * S, 0);
  // Scores: per batch M=N=S, K=D; C fp32, alpha = 1/32
  const dim3 g2(S / BN, S / BM, Bb);
  gemm_bf16<M_SC><<<g2, blk, 0, stream>>>(Qb, Kb, Sbuf, nullptr, 0.03125f, D, D, D, S,
                                          (size_t)S * D, (size_t)S * D, (size_t)S * S, 0);
  // Softmax -> P bf16 in-place (row stride stays 8KB => 4096 bf16 elements)
  softmax2048_bf16<<<dim3((int)BS), blk, 0, stream>>>(Sbuf);
  // PV: per batch M=S, N=D, K=S; A=P(lda 4096), B=Vt(ldb S); + residual x
  const dim3 g3(D / BN, S / BM, Bb);
  gemm_bf16<M_PV><<<g3, blk, 0, stream>>>(
      (const unsigned short*)Sbuf, Vt, out, x, 1.f, S, 2 * S, S, D,
      (size_t)S * 2 * S, (size_t)D * S, (size_t)S * D, (size_t)S * D);
  // LayerNorm
  ln1024<<<dim3((int)BS), dim3(64), 0, stream>>>(out, gamma, beta);
}

// Round 4
// 523.908 us; speedup vs baseline: 5.5998x; 1.1719x over previous
//
#include <hip/hip_runtime.h>

// Self-attention block: bf16 MFMA GEMMs in the 256x256/BK=64 8-phase
// counted-vmcnt structure (T2 swizzle + T3/T4 pipeline + T5 setprio).
//   B=8, S=2048, D=1024
// Pipeline: f32->bf16 converts (x, Wq|Wk|Wv concat); fused QKV projection
// (Q,K bf16; V transposed -> Vt); scores = Q K^T/32 (f32); softmax (bf16 P
// in-place); PV NT-GEMM + residual (f32); LayerNorm.
// GEMM: 512 thr = 8 waves, wave = 32 rows x 256 cols (acc[2][16] f32x4).
// K-tile = 64. LDS 128KB: 2 bufs x (A 32KB + B 32KB), XOR-swizzled
// (byte bits5-6 ^= row bits2-3), staged via global_load_lds w/ pre-swizzled
// per-lane global source (linear LDS dest). Per K-tile: stage next tile (8
// loads, fixed order A,Bq0..Bq3) at P1; 4 phases x {counted vmcnt, s_barrier,
// ds_read frags, lgkmcnt(0), 16 MFMA in setprio(1)}. Waits: P1 vmcnt(3),
// P2-P4 vmcnt(10/9/8); last tile 3/2/1/0 (provable ledger; never drain in
// steady state).
// ws (256MB): xb|Qb|Kb|Vt bf16 (128MB) + Sbuf f32 (128MB; Wcat bf16 in head,
// dead before scores write).

typedef __bf16 bf16x8 __attribute__((ext_vector_type(8)));
typedef float f32x4 __attribute__((ext_vector_type(4)));

enum { M_QKV = 0, M_SC = 1, M_PV = 2 };

__device__ __forceinline__ unsigned short f2b(float f) {
  union { float f; unsigned int u; } v; v.f = f;
  return (unsigned short)((v.u + 0x7FFFu + ((v.u >> 16) & 1u)) >> 16);
}

#define GL16(gsrc, ldst)                                         \
  __builtin_amdgcn_global_load_lds(                              \
      (const __attribute__((address_space(1))) void*)(gsrc),     \
      (__attribute__((address_space(3))) void*)(ldst), 16, 0, 0)

// Stage one 256x64 bf16 tile pair (A,B) for K-tile tau into LDS buffer b.
// Issue order pinned: A r0..r3 then B r0..r3 (vmcnt ledger depends on it).
__device__ __forceinline__ void stage_tile(
    const unsigned short* Ab, const unsigned short* Bb, char* lds,
    int b, int tau, int gm0, int gn0, int ldaE, int ldbE, int t)
{
  const int kc = tau << 6;
  const int row4 = t >> 3;            // 0..63 within each 64-row chunk
  const int c = (t & 7) << 4;         // byte col 0..112
  const int wb = (t & ~63) * 16;      // wave-uniform LDS base portion
#pragma unroll
  for (int r = 0; r < 4; ++r) {
    const int row = r * 64 + row4;
    const int cs = c ^ ((row & 12) << 3);   // pre-swizzled source col
    GL16((const char*)(Ab + (size_t)(gm0 + row) * ldaE + kc) + cs,
         lds + b * 65536 + r * 8192 + wb);
    __builtin_amdgcn_sched_barrier(0);
  }
#pragma unroll
  for (int r = 0; r < 4; ++r) {
    const int row = r * 64 + row4;
    const int cs = c ^ ((row & 12) << 3);
    GL16((const char*)(Bb + (size_t)(gn0 + row) * ldbE + kc) + cs,
         lds + b * 65536 + 32768 + r * 8192 + wb);
    __builtin_amdgcn_sched_barrier(0);
  }
}

// Swizzled LDS fragment read: logical (row, byte-col kb) of a [256][64] tile.
__device__ __forceinline__ bf16x8 ldsrd(const char* lds, int base, int row, int kb) {
  int p = row * 128 + kb;
  p ^= (p & 0x600) >> 4;              // byte bits5-6 ^= row bits2-3
  return *(const bf16x8*)(lds + base + p);
}

template <int MODE>
__global__ __launch_bounds__(512, 2) void gemm8(
    const unsigned short* __restrict__ A, const unsigned short* __restrict__ B,
    void* __restrict__ C0, void* __restrict__ C1, void* __restrict__ C2,
    const float* __restrict__ x0, const float* __restrict__ x1,
    const float* __restrict__ x2,
    int K, int ldaE, int ldbE, size_t sA, size_t sB)
{
  extern __shared__ char lds[];
  const int t = threadIdx.x, l = t & 63, w = t >> 6;
  const int bz = blockIdx.z;
  const unsigned short* Ab = A + (size_t)bz * sA;
  const unsigned short* Bb = B + (size_t)bz * sB;
  const int gm0 = blockIdx.y * 256, gn0 = blockIdx.x * 256;
  const int lo16 = l & 15, hi4 = l >> 4;
  const int kb0 = hi4 * 16;
  const int nt = K >> 6;

  f32x4 acc[2][16];
#pragma unroll
  for (int i = 0; i < 2; ++i)
#pragma unroll
    for (int j = 0; j < 16; ++j) acc[i][j] = f32x4{0.f, 0.f, 0.f, 0.f};

  stage_tile(Ab, Bb, lds, 0, 0, gm0, gn0, ldaE, ldbE, t);

  bf16x8 af[2][2];
  for (int tau = 0; tau < nt; ++tau) {
    const int abase = (tau & 1) * 65536, bbase = abase + 32768;
    const bool more = (tau + 1) < nt;
    // ---------- P1 ----------
    asm volatile("s_waitcnt vmcnt(3)" ::: "memory");
    __builtin_amdgcn_sched_barrier(0);
    __builtin_amdgcn_s_barrier();
    __builtin_amdgcn_sched_barrier(0);
    if (more)
      stage_tile(Ab, Bb, lds, (tau & 1) ^ 1, tau + 1, gm0, gn0, ldaE, ldbE, t);
    bf16x8 bf[4][2];
#pragma unroll
    for (int mf = 0; mf < 2; ++mf)
#pragma unroll
      for (int ks = 0; ks < 2; ++ks)
        af[mf][ks] = ldsrd(lds, abase, w * 32 + mf * 16 + lo16, ks * 64 + kb0);
#pragma unroll
    for (int nf = 0; nf < 4; ++nf)
#pragma unroll
      for (int ks = 0; ks < 2; ++ks)
        bf[nf][ks] = ldsrd(lds, bbase, nf * 16 + lo16, ks * 64 + kb0);
    asm volatile("s_waitcnt lgkmcnt(0)" ::: "memory");
    __builtin_amdgcn_sched_barrier(0);
    __builtin_amdgcn_s_setprio(1);
#pragma unroll
    for (int mf = 0; mf < 2; ++mf)
#pragma unroll
      for (int nf = 0; nf < 4; ++nf)
#pragma unroll
        for (int ks = 0; ks < 2; ++ks)
          acc[mf][nf] = __builtin_amdgcn_mfma_f32_16x16x32_bf16(
              af[mf][ks], bf[nf][ks], acc[mf][nf], 0, 0, 0);
    __builtin_amdgcn_s_setprio(0);
    // ---------- P2..P4 ----------
#pragma unroll
    for (int p = 1; p < 4; ++p) {
      if (p == 1) {
        if (more) asm volatile("s_waitcnt vmcnt(10)" ::: "memory");
        else      asm volatile("s_waitcnt vmcnt(2)" ::: "memory");
      } else if (p == 2) {
        if (more) asm volatile("s_waitcnt vmcnt(9)" ::: "memory");
        else      asm volatile("s_waitcnt vmcnt(1)" ::: "memory");
      } else {
        if (more) asm volatile("s_waitcnt vmcnt(8)" ::: "memory");
        else      asm volatile("s_waitcnt vmcnt(0)" ::: "memory");
      }
      __builtin_amdgcn_sched_barrier(0);
      __builtin_amdgcn_s_barrier();
      __builtin_amdgcn_sched_barrier(0);
#pragma unroll
      for (int nf = 0; nf < 4; ++nf)
#pragma unroll
        for (int ks = 0; ks < 2; ++ks)
          bf[nf][ks] = ldsrd(lds, bbase, (p * 4 + nf) * 16 + lo16, ks * 64 + kb0);
      asm volatile("s_waitcnt lgkmcnt(0)" ::: "memory");
      __builtin_amdgcn_sched_barrier(0);
      __builtin_amdgcn_s_setprio(1);
#pragma unroll
      for (int mf = 0; mf < 2; ++mf)
#pragma unroll
        for (int nf = 0; nf < 4; ++nf)
#pragma unroll
          for (int ks = 0; ks < 2; ++ks)
            acc[mf][p * 4 + nf] = __builtin_amdgcn_mfma_f32_16x16x32_bf16(
                af[mf][ks], bf[nf][ks], acc[mf][p * 4 + nf], 0, 0, 0);
      __builtin_amdgcn_s_setprio(0);
    }
  }

  // Epilogue. Frag (mf,nf): rows gm0+w*32+mf*16+hi4*4+r, col gn0+nf*16+lo16.
#pragma unroll
  for (int mf = 0; mf < 2; ++mf) {
    const int grow = gm0 + w * 32 + mf * 16 + hi4 * 4;
#pragma unroll
    for (int nf = 0; nf < 16; ++nf) {
      const int gc = gn0 + nf * 16 + lo16;
      if constexpr (MODE == M_QKV) {
        // C0=Qb, C1=Kb (row-major [16384][1024]); C2=Vt ([8][1024][2048]).
        if (gc < 1024) {
          unsigned short* Q = (unsigned short*)C0;
          const float b = x0[gc];
#pragma unroll
          for (int r = 0; r < 4; ++r)
            Q[(size_t)(grow + r) * 1024 + gc] = f2b(acc[mf][nf][r] + b);
        } else if (gc < 2048) {
          unsigned short* Kk = (unsigned short*)C1;
          const float b = x1[gc - 1024];
#pragma unroll
          for (int r = 0; r < 4; ++r)
            Kk[(size_t)(grow + r) * 1024 + (gc - 1024)] = f2b(acc[mf][nf][r] + b);
        } else {
          unsigned short* Vt = (unsigned short*)C2;
          const float b = x2[gc - 2048];
          const int bat = grow >> 11, lm = grow & 2047;
          ushort4 o = make_ushort4(
              f2b(acc[mf][nf][0] + b), f2b(acc[mf][nf][1] + b),
              f2b(acc[mf][nf][2] + b), f2b(acc[mf][nf][3] + b));
          *(ushort4*)&Vt[(size_t)bat * 2097152 + (size_t)(gc - 2048) * 2048 + lm] = o;
        }
      } else if constexpr (MODE == M_SC) {
        float* C = (float*)C0 + (size_t)bz * 4194304;  // S*S
        float* p = C + (size_t)grow * 2048 + gc;
#pragma unroll
        for (int r = 0; r < 4; ++r) p[(size_t)r * 2048] = acc[mf][nf][r] * 0.03125f;
      } else {  // M_PV: += residual, f32 out
        float* C = (float*)C0 + (size_t)bz * 2097152;  // S*D
        const float* R = x0 + (size_t)bz * 2097152;
        float* p = C + (size_t)grow * 1024 + gc;
        const float* q = R + (size_t)grow * 1024 + gc;
#pragma unroll
        for (int r = 0; r < 4; ++r) p[(size_t)r * 1024] = acc[mf][nf][r] + q[(size_t)r * 1024];
      }
    }
  }
}

__global__ __launch_bounds__(256) void f32_to_bf16(
    const float* __restrict__ s, unsigned short* __restrict__ d)
{
  const size_t i = (size_t)blockIdx.x * 256 + threadIdx.x;
  const float4 a = ((const float4*)s)[i * 2];
  const float4 b = ((const float4*)s)[i * 2 + 1];
  ((ushort4*)d)[i * 2]     = make_ushort4(f2b(a.x), f2b(a.y), f2b(a.z), f2b(a.w));
  ((ushort4*)d)[i * 2 + 1] = make_ushort4(f2b(b.x), f2b(b.y), f2b(b.z), f2b(b.w));
}

// Row softmax, fp32 in (row of 2048), bf16 out written in-place at row head.
__global__ __launch_bounds__(256) void softmax2048_bf16(float* __restrict__ S)
{
  __shared__ float redm[4];
  __shared__ float reds[4];
  const int t = threadIdx.x;
  float* p = S + (size_t)blockIdx.x * 2048;
  float4 a = *(const float4*)&p[t * 4];
  float4 b = *(const float4*)&p[t * 4 + 1024];
  float m = fmaxf(fmaxf(fmaxf(a.x, a.y), fmaxf(a.z, a.w)),
                  fmaxf(fmaxf(b.x, b.y), fmaxf(b.z, b.w)));
#pragma unroll
  for (int o = 32; o; o >>= 1) m = fmaxf(m, __shfl_xor(m, o));
  if ((t & 63) == 0) redm[t >> 6] = m;
  __syncthreads();
  m = fmaxf(fmaxf(redm[0], redm[1]), fmaxf(redm[2], redm[3]));
  a.x = __expf(a.x - m); a.y = __expf(a.y - m);
  a.z = __expf(a.z - m); a.w = __expf(a.w - m);
  b.x = __expf(b.x - m); b.y = __expf(b.y - m);
  b.z = __expf(b.z - m); b.w = __expf(b.w - m);
  float s = a.x + a.y + a.z + a.w + b.x + b.y + b.z + b.w;
#pragma unroll
  for (int o = 32; o; o >>= 1) s += __shfl_xor(s, o);
  if ((t & 63) == 0) reds[t >> 6] = s;
  __syncthreads();
  s = reds[0] + reds[1] + reds[2] + reds[3];
  const float inv = 1.0f / s;
  unsigned short* pb = (unsigned short*)p;
  *(ushort4*)&pb[t * 4] =
      make_ushort4(f2b(a.x * inv), f2b(a.y * inv), f2b(a.z * inv), f2b(a.w * inv));
  *(ushort4*)&pb[1024 + t * 4] =
      make_ushort4(f2b(b.x * inv), f2b(b.y * inv), f2b(b.z * inv), f2b(b.w * inv));
}

// In-place LayerNorm over D=1024, one wave per row.
__global__ __launch_bounds__(64) void ln1024(
    float* __restrict__ O, const float* __restrict__ g, const float* __restrict__ be)
{
  const int l = threadIdx.x;
  float* p = O + (size_t)blockIdx.x * 1024;
  float4 v[4];
#pragma unroll
  for (int i = 0; i < 4; ++i) v[i] = *(const float4*)&p[l * 4 + i * 256];
  float s = 0.f, q = 0.f;
#pragma unroll
  for (int i = 0; i < 4; ++i) {
    s += v[i].x + v[i].y + v[i].z + v[i].w;
    q += v[i].x * v[i].x + v[i].y * v[i].y + v[i].z * v[i].z + v[i].w * v[i].w;
  }
#pragma unroll
  for (int o = 32; o; o >>= 1) { s += __shfl_xor(s, o); q += __shfl_xor(q, o); }
  const float mu = s * (1.0f / 1024.0f);
  const float var = q * (1.0f / 1024.0f) - mu * mu;
  const float rs = rsqrtf(var + 1e-5f);
#pragma unroll
  for (int i = 0; i < 4; ++i) {
    const float4 gg = *(const float4*)&g[l * 4 + i * 256];
    const float4 bb = *(const float4*)&be[l * 4 + i * 256];
    float4 o4;
    o4.x = (v[i].x - mu) * rs * gg.x + bb.x;
    o4.y = (v[i].y - mu) * rs * gg.y + bb.y;
    o4.z = (v[i].z - mu) * rs * gg.z + bb.z;
    o4.w = (v[i].w - mu) * rs * gg.w + bb.w;
    *(float4*)&p[l * 4 + i * 256] = o4;
  }
}

extern "C" void kernel_launch(void* const* d_in, const int* in_sizes, int n_in,
                              void* d_out, int out_size, void* d_ws, size_t ws_size,
                              hipStream_t stream) {
  (void)in_sizes; (void)n_in; (void)out_size; (void)ws_size;
  constexpr int Bb = 8, S = 2048, D = 1024;
  const size_t BS = (size_t)Bb * S;
  const size_t ND = BS * (size_t)D;

  const float* x     = (const float*)d_in[0];
  const float* Wq    = (const float*)d_in[1];
  const float* bq    = (const float*)d_in[2];
  const float* Wk    = (const float*)d_in[3];
  const float* bk    = (const float*)d_in[4];
  const float* Wv    = (const float*)d_in[5];
  const float* bv    = (const float*)d_in[6];
  const float* gamma = (const float*)d_in[7];
  const float* beta  = (const float*)d_in[8];
  float* out = (float*)d_out;

  unsigned short* xb = (unsigned short*)d_ws;
  unsigned short* Qb = xb + ND;
  unsigned short* Kb = Qb + ND;
  unsigned short* Vt = Kb + ND;
  float* Sbuf = (float*)(Vt + ND);
  unsigned short* Wcat = (unsigned short*)Sbuf;  // [3072][1024], dead by scores

  hipFuncSetAttribute((const void*)gemm8<M_QKV>,
                      hipFuncAttributeMaxDynamicSharedMemorySize, 131072);
  hipFuncSetAttribute((const void*)gemm8<M_SC>,
                      hipFuncAttributeMaxDynamicSharedMemorySize, 131072);
  hipFuncSetAttribute((const void*)gemm8<M_PV>,
                      hipFuncAttributeMaxDynamicSharedMemorySize, 131072);

  f32_to_bf16<<<dim3(8192), dim3(256), 0, stream>>>(x, xb);
  f32_to_bf16<<<dim3(512), dim3(256), 0, stream>>>(Wq, Wcat);
  f32_to_bf16<<<dim3(512), dim3(256), 0, stream>>>(Wk, Wcat + (size_t)D * D);
  f32_to_bf16<<<dim3(512), dim3(256), 0, stream>>>(Wv, Wcat + 2 * (size_t)D * D);

  // Fused QKV: M=16384, N=3072, K=1024
  gemm8<M_QKV><<<dim3(12, 64, 1), dim3(512), 131072, stream>>>(
      xb, Wcat, Qb, Kb, Vt, bq, bk, bv, D, D, D, 0, 0);
  // Scores: per batch M=N=2048, K=1024
  gemm8<M_SC><<<dim3(8, 8, 8), dim3(512), 131072, stream>>>(
      Qb, Kb, Sbuf, nullptr, nullptr, nullptr, nullptr, nullptr,
      D, D, D, (size_t)S * D, (size_t)S * D);
  softmax2048_bf16<<<dim3((int)BS), dim3(256), 0, stream>>>(Sbuf);
  // PV: per batch M=2048, N=1024, K=2048; A=P (lda 4096), B=Vt (ldb 2048)
  gemm8<M_PV><<<dim3(4, 8, 8), dim3(512), 131072, stream>>>(
      (const unsigned short*)Sbuf, Vt, out, nullptr, nullptr, x, nullptr, nullptr,
      S, 2 * S, S, (size_t)S * 2 * S, (size_t)D * S);
  ln1024<<<dim3((int)BS), dim3(64), 0, stream>>>(out, gamma, beta);
}

// Round 5
// 518.453 us; speedup vs baseline: 5.6587x; 1.0105x over previous
//
#include <hip/hip_runtime.h>

// Self-attention block: bf16 MFMA GEMMs, 256x256/BK=64, 4-phase counted-vmcnt
// pipeline with FRAGMENT-CONTIGUOUS LDS (zero bank conflicts by construction).
//   B=8, S=2048, D=1024
// GEMM: 512 thr = 8 waves in 2x4 (wave tile 128x64, acc[8][4] f32x4).
// LDS 128KB = 2 bufs x (A 32KB | B 32KB); each 16-row x 32-K fragment is a
// contiguous 1024B unit (unit*1024 + lane*16), written by global_load_lds
// with pre-permuted per-lane global source (linear LDS dest, rule #21).
// Per K-tile, per wave: stage 8 units of tile tau+1 at P0 in fixed order
// s0..s7 = [A-P0 ks0/1, B-P0 ks0/1, B-P1 ks0/1, A-P2 ks0/1]; phases:
//   P0 (mh0,nh0): vmcnt(4),  barrier, stage, read a+b0, 16 MFMA
//   P1 (mh0,nh1): vmcnt(10), barrier, read b1,          16 MFMA
//   P2 (mh1,nh1): vmcnt(8),  barrier, read a',          16 MFMA
//   P3 (mh1,nh0): no wait/barrier (regs held),          16 MFMA
// Last tile waits 4/2/0. Never drains in steady state (T3+T4), setprio (T5).
// ws (256MB): xb|Qb|Kb|Vt bf16 (128MB) + Sbuf f32 (128MB; Wcat bf16 in head).

typedef __bf16 bf16x8 __attribute__((ext_vector_type(8)));
typedef float f32x4 __attribute__((ext_vector_type(4)));

enum { M_QKV = 0, M_SC = 1, M_PV = 2 };

__device__ __forceinline__ unsigned short f2b(float f) {
  union { float f; unsigned int u; } v; v.f = f;
  return (unsigned short)((v.u + 0x7FFFu + ((v.u >> 16) & 1u)) >> 16);
}

#define GL16(gsrc, ldst)                                         \
  __builtin_amdgcn_global_load_lds(                              \
      (const __attribute__((address_space(1))) void*)(gsrc),     \
      (__attribute__((address_space(3))) void*)(ldst), 16, 0, 0)

template <int MODE>
__global__ __launch_bounds__(512, 2) void gemm8(
    const unsigned short* __restrict__ A, const unsigned short* __restrict__ B,
    void* __restrict__ C0, void* __restrict__ C1, void* __restrict__ C2,
    const float* __restrict__ x0, const float* __restrict__ x1,
    const float* __restrict__ x2,
    int K, int ldaE, int ldbE, size_t sA, size_t sB)
{
  extern __shared__ char lds[];
  const int t = threadIdx.x, l = t & 63, w = t >> 6;
  const int wm = w >> 2, wn = w & 3;          // 2x4 wave grid
  const int rl = l & 15, hi4 = l >> 4;
  const int cl8 = hi4 * 8;                    // k-elem offset within 32-block
  const int bz = blockIdx.z;
  const unsigned short* Ab = A + (size_t)bz * sA;
  const unsigned short* Bb = B + (size_t)bz * sB;
  const int gm0 = blockIdx.y * 256, gn0 = blockIdx.x * 256;
  const int nt = K >> 6;

  // Per-wave staging assignment (units this wave writes each K-tile).
  const int frA0 = (w & 3) + (w >> 2) * 8;    // {0..3,8..11}: A mh0 set
  const int frB0 = (w >> 1) * 4 + (w & 1);    // {0,1,4,5,8,9,12,13}: B nh0 set

  const unsigned short* sp[8];
  int ub[8];
  sp[0] = Ab + (size_t)(gm0 + frA0 * 16 + rl) * ldaE + cl8;        // A-P0 ks0
  sp[1] = sp[0] + 32;                                              // A-P0 ks1
  sp[2] = Bb + (size_t)(gn0 + frB0 * 16 + rl) * ldbE + cl8;        // B-P0 ks0
  sp[3] = sp[2] + 32;
  sp[4] = Bb + (size_t)(gn0 + (frB0 + 2) * 16 + rl) * ldbE + cl8;  // B-P1 ks0
  sp[5] = sp[4] + 32;
  sp[6] = Ab + (size_t)(gm0 + (frA0 + 4) * 16 + rl) * ldaE + cl8;  // A-P2 ks0
  sp[7] = sp[6] + 32;
  ub[0] = frA0 * 2048;             ub[1] = ub[0] + 1024;
  ub[2] = 32768 + frB0 * 2048;     ub[3] = ub[2] + 1024;
  ub[4] = 32768 + (frB0 + 2) * 2048; ub[5] = ub[4] + 1024;
  ub[6] = (frA0 + 4) * 2048;       ub[7] = ub[6] + 1024;

  auto stage = [&](int tau, int buf) {
#pragma unroll
    for (int s = 0; s < 8; ++s) {
      GL16(sp[s] + (size_t)tau * 64, lds + buf * 65536 + ub[s]);
      __builtin_amdgcn_sched_barrier(0);
    }
  };

  f32x4 acc[8][4];
#pragma unroll
  for (int i = 0; i < 8; ++i)
#pragma unroll
    for (int j = 0; j < 4; ++j) acc[i][j] = f32x4{0.f, 0.f, 0.f, 0.f};

  stage(0, 0);

  const int lb = l * 16;
  bf16x8 a[4][2], b0[2][2], b1[2][2];

  for (int tau = 0; tau < nt; ++tau) {
    const char* bp = lds + (tau & 1) * 65536;
    const bool more = (tau + 1) < nt;
    // -------- P0: quadrant (mh0, nh0) --------
    asm volatile("s_waitcnt vmcnt(4)" ::: "memory");
    __builtin_amdgcn_sched_barrier(0);
    __builtin_amdgcn_s_barrier();
    __builtin_amdgcn_sched_barrier(0);
    if (more) stage(tau + 1, (tau & 1) ^ 1);
#pragma unroll
    for (int mf = 0; mf < 4; ++mf)
#pragma unroll
      for (int ks = 0; ks < 2; ++ks)
        a[mf][ks] = *(const bf16x8*)(bp + ((wm * 8 + mf) * 2 + ks) * 1024 + lb);
#pragma unroll
    for (int nf = 0; nf < 2; ++nf)
#pragma unroll
      for (int ks = 0; ks < 2; ++ks)
        b0[nf][ks] = *(const bf16x8*)(bp + 32768 + ((wn * 4 + nf) * 2 + ks) * 1024 + lb);
    asm volatile("s_waitcnt lgkmcnt(0)" ::: "memory");
    __builtin_amdgcn_sched_barrier(0);
    __builtin_amdgcn_s_setprio(1);
#pragma unroll
    for (int mf = 0; mf < 4; ++mf)
#pragma unroll
      for (int nf = 0; nf < 2; ++nf)
#pragma unroll
        for (int ks = 0; ks < 2; ++ks)
          acc[mf][nf] = __builtin_amdgcn_mfma_f32_16x16x32_bf16(
              a[mf][ks], b0[nf][ks], acc[mf][nf], 0, 0, 0);
    __builtin_amdgcn_s_setprio(0);
    // -------- P1: (mh0, nh1) --------
    if (more) asm volatile("s_waitcnt vmcnt(10)" ::: "memory");
    else      asm volatile("s_waitcnt vmcnt(2)"  ::: "memory");
    __builtin_amdgcn_sched_barrier(0);
    __builtin_amdgcn_s_barrier();
    __builtin_amdgcn_sched_barrier(0);
#pragma unroll
    for (int nf = 0; nf < 2; ++nf)
#pragma unroll
      for (int ks = 0; ks < 2; ++ks)
        b1[nf][ks] = *(const bf16x8*)(bp + 32768 + ((wn * 4 + 2 + nf) * 2 + ks) * 1024 + lb);
    asm volatile("s_waitcnt lgkmcnt(0)" ::: "memory");
    __builtin_amdgcn_sched_barrier(0);
    __builtin_amdgcn_s_setprio(1);
#pragma unroll
    for (int mf = 0; mf < 4; ++mf)
#pragma unroll
      for (int nf = 0; nf < 2; ++nf)
#pragma unroll
        for (int ks = 0; ks < 2; ++ks)
          acc[mf][2 + nf] = __builtin_amdgcn_mfma_f32_16x16x32_bf16(
              a[mf][ks], b1[nf][ks], acc[mf][2 + nf], 0, 0, 0);
    __builtin_amdgcn_s_setprio(0);
    // -------- P2: (mh1, nh1) --------
    if (more) asm volatile("s_waitcnt vmcnt(8)" ::: "memory");
    else      asm volatile("s_waitcnt vmcnt(0)" ::: "memory");
    __builtin_amdgcn_sched_barrier(0);
    __builtin_amdgcn_s_barrier();
    __builtin_amdgcn_sched_barrier(0);
#pragma unroll
    for (int mf = 0; mf < 4; ++mf)
#pragma unroll
      for (int ks = 0; ks < 2; ++ks)
        a[mf][ks] = *(const bf16x8*)(bp + ((wm * 8 + 4 + mf) * 2 + ks) * 1024 + lb);
    asm volatile("s_waitcnt lgkmcnt(0)" ::: "memory");
    __builtin_amdgcn_sched_barrier(0);
    __builtin_amdgcn_s_setprio(1);
#pragma unroll
    for (int mf = 0; mf < 4; ++mf)
#pragma unroll
      for (int nf = 0; nf < 2; ++nf)
#pragma unroll
        for (int ks = 0; ks < 2; ++ks)
          acc[4 + mf][2 + nf] = __builtin_amdgcn_mfma_f32_16x16x32_bf16(
              a[mf][ks], b1[nf][ks], acc[4 + mf][2 + nf], 0, 0, 0);
    __builtin_amdgcn_s_setprio(0);
    // -------- P3: (mh1, nh0) -- register-held operands, no wait/barrier ----
    __builtin_amdgcn_s_setprio(1);
#pragma unroll
    for (int mf = 0; mf < 4; ++mf)
#pragma unroll
      for (int nf = 0; nf < 2; ++nf)
#pragma unroll
        for (int ks = 0; ks < 2; ++ks)
          acc[4 + mf][nf] = __builtin_amdgcn_mfma_f32_16x16x32_bf16(
              a[mf][ks], b0[nf][ks], acc[4 + mf][nf], 0, 0, 0);
    __builtin_amdgcn_s_setprio(0);
  }

  // Epilogue. Frag (Mf,Nf): rows gm0+wm*128+Mf*16+hi4*4+r, col gn0+wn*64+Nf*16+rl.
#pragma unroll
  for (int Mf = 0; Mf < 8; ++Mf) {
    const int grow = gm0 + wm * 128 + Mf * 16 + hi4 * 4;
#pragma unroll
    for (int Nf = 0; Nf < 4; ++Nf) {
      const int gc = gn0 + wn * 64 + Nf * 16 + rl;
      if constexpr (MODE == M_QKV) {
        if (gc < 1024) {
          unsigned short* Q = (unsigned short*)C0;
          const float b = x0[gc];
#pragma unroll
          for (int r = 0; r < 4; ++r)
            Q[(size_t)(grow + r) * 1024 + gc] = f2b(acc[Mf][Nf][r] + b);
        } else if (gc < 2048) {
          unsigned short* Kk = (unsigned short*)C1;
          const float b = x1[gc - 1024];
#pragma unroll
          for (int r = 0; r < 4; ++r)
            Kk[(size_t)(grow + r) * 1024 + (gc - 1024)] = f2b(acc[Mf][Nf][r] + b);
        } else {
          unsigned short* Vt = (unsigned short*)C2;
          const float b = x2[gc - 2048];
          const int bat = grow >> 11, lm = grow & 2047;
          ushort4 o = make_ushort4(
              f2b(acc[Mf][Nf][0] + b), f2b(acc[Mf][Nf][1] + b),
              f2b(acc[Mf][Nf][2] + b), f2b(acc[Mf][Nf][3] + b));
          *(ushort4*)&Vt[(size_t)bat * 2097152 + (size_t)(gc - 2048) * 2048 + lm] = o;
        }
      } else if constexpr (MODE == M_SC) {
        float* C = (float*)C0 + (size_t)bz * 4194304;
        float* p = C + (size_t)grow * 2048 + gc;
#pragma unroll
        for (int r = 0; r < 4; ++r) p[(size_t)r * 2048] = acc[Mf][Nf][r] * 0.03125f;
      } else {  // M_PV
        float* C = (float*)C0 + (size_t)bz * 2097152;
        const float* R = x0 + (size_t)bz * 2097152;
        float* p = C + (size_t)grow * 1024 + gc;
        const float* q = R + (size_t)grow * 1024 + gc;
#pragma unroll
        for (int r = 0; r < 4; ++r) p[(size_t)r * 1024] = acc[Mf][Nf][r] + q[(size_t)r * 1024];
      }
    }
  }
}

__global__ __launch_bounds__(256) void f32_to_bf16(
    const float* __restrict__ s, unsigned short* __restrict__ d)
{
  const size_t i = (size_t)blockIdx.x * 256 + threadIdx.x;
  const float4 a = ((const float4*)s)[i * 2];
  const float4 b = ((const float4*)s)[i * 2 + 1];
  ((ushort4*)d)[i * 2]     = make_ushort4(f2b(a.x), f2b(a.y), f2b(a.z), f2b(a.w));
  ((ushort4*)d)[i * 2 + 1] = make_ushort4(f2b(b.x), f2b(b.y), f2b(b.z), f2b(b.w));
}

// Row softmax, fp32 in (row of 2048), bf16 out written in-place at row head.
__global__ __launch_bounds__(256) void softmax2048_bf16(float* __restrict__ S)
{
  __shared__ float redm[4];
  __shared__ float reds[4];
  const int t = threadIdx.x;
  float* p = S + (size_t)blockIdx.x * 2048;
  float4 a = *(const float4*)&p[t * 4];
  float4 b = *(const float4*)&p[t * 4 + 1024];
  float m = fmaxf(fmaxf(fmaxf(a.x, a.y), fmaxf(a.z, a.w)),
                  fmaxf(fmaxf(b.x, b.y), fmaxf(b.z, b.w)));
#pragma unroll
  for (int o = 32; o; o >>= 1) m = fmaxf(m, __shfl_xor(m, o));
  if ((t & 63) == 0) redm[t >> 6] = m;
  __syncthreads();
  m = fmaxf(fmaxf(redm[0], redm[1]), fmaxf(redm[2], redm[3]));
  a.x = __expf(a.x - m); a.y = __expf(a.y - m);
  a.z = __expf(a.z - m); a.w = __expf(a.w - m);
  b.x = __expf(b.x - m); b.y = __expf(b.y - m);
  b.z = __expf(b.z - m); b.w = __expf(b.w - m);
  float s = a.x + a.y + a.z + a.w + b.x + b.y + b.z + b.w;
#pragma unroll
  for (int o = 32; o; o >>= 1) s += __shfl_xor(s, o);
  if ((t & 63) == 0) reds[t >> 6] = s;
  __syncthreads();
  s = reds[0] + reds[1] + reds[2] + reds[3];
  const float inv = 1.0f / s;
  unsigned short* pb = (unsigned short*)p;
  *(ushort4*)&pb[t * 4] =
      make_ushort4(f2b(a.x * inv), f2b(a.y * inv), f2b(a.z * inv), f2b(a.w * inv));
  *(ushort4*)&pb[1024 + t * 4] =
      make_ushort4(f2b(b.x * inv), f2b(b.y * inv), f2b(b.z * inv), f2b(b.w * inv));
}

// In-place LayerNorm over D=1024, one wave per row.
__global__ __launch_bounds__(64) void ln1024(
    float* __restrict__ O, const float* __restrict__ g, const float* __restrict__ be)
{
  const int l = threadIdx.x;
  float* p = O + (size_t)blockIdx.x * 1024;
  float4 v[4];
#pragma unroll
  for (int i = 0; i < 4; ++i) v[i] = *(const float4*)&p[l * 4 + i * 256];
  float s = 0.f, q = 0.f;
#pragma unroll
  for (int i = 0; i < 4; ++i) {
    s += v[i].x + v[i].y + v[i].z + v[i].w;
    q += v[i].x * v[i].x + v[i].y * v[i].y + v[i].z * v[i].z + v[i].w * v[i].w;
  }
#pragma unroll
  for (int o = 32; o; o >>= 1) { s += __shfl_xor(s, o); q += __shfl_xor(q, o); }
  const float mu = s * (1.0f / 1024.0f);
  const float var = q * (1.0f / 1024.0f) - mu * mu;
  const float rs = rsqrtf(var + 1e-5f);
#pragma unroll
  for (int i = 0; i < 4; ++i) {
    const float4 gg = *(const float4*)&g[l * 4 + i * 256];
    const float4 bb = *(const float4*)&be[l * 4 + i * 256];
    float4 o4;
    o4.x = (v[i].x - mu) * rs * gg.x + bb.x;
    o4.y = (v[i].y - mu) * rs * gg.y + bb.y;
    o4.z = (v[i].z - mu) * rs * gg.z + bb.z;
    o4.w = (v[i].w - mu) * rs * gg.w + bb.w;
    *(float4*)&p[l * 4 + i * 256] = o4;
  }
}

extern "C" void kernel_launch(void* const* d_in, const int* in_sizes, int n_in,
                              void* d_out, int out_size, void* d_ws, size_t ws_size,
                              hipStream_t stream) {
  (void)in_sizes; (void)n_in; (void)out_size; (void)ws_size;
  constexpr int Bb = 8, S = 2048, D = 1024;
  const size_t BS = (size_t)Bb * S;
  const size_t ND = BS * (size_t)D;

  const float* x     = (const float*)d_in[0];
  const float* Wq    = (const float*)d_in[1];
  const float* bq    = (const float*)d_in[2];
  const float* Wk    = (const float*)d_in[3];
  const float* bk    = (const float*)d_in[4];
  const float* Wv    = (const float*)d_in[5];
  const float* bv    = (const float*)d_in[6];
  const float* gamma = (const float*)d_in[7];
  const float* beta  = (const float*)d_in[8];
  float* out = (float*)d_out;

  unsigned short* xb = (unsigned short*)d_ws;
  unsigned short* Qb = xb + ND;
  unsigned short* Kb = Qb + ND;
  unsigned short* Vt = Kb + ND;
  float* Sbuf = (float*)(Vt + ND);
  unsigned short* Wcat = (unsigned short*)Sbuf;  // [3072][1024], dead by scores

  hipFuncSetAttribute((const void*)gemm8<M_QKV>,
                      hipFuncAttributeMaxDynamicSharedMemorySize, 131072);
  hipFuncSetAttribute((const void*)gemm8<M_SC>,
                      hipFuncAttributeMaxDynamicSharedMemorySize, 131072);
  hipFuncSetAttribute((const void*)gemm8<M_PV>,
                      hipFuncAttributeMaxDynamicSharedMemorySize, 131072);

  f32_to_bf16<<<dim3(8192), dim3(256), 0, stream>>>(x, xb);
  f32_to_bf16<<<dim3(512), dim3(256), 0, stream>>>(Wq, Wcat);
  f32_to_bf16<<<dim3(512), dim3(256), 0, stream>>>(Wk, Wcat + (size_t)D * D);
  f32_to_bf16<<<dim3(512), dim3(256), 0, stream>>>(Wv, Wcat + 2 * (size_t)D * D);

  // Fused QKV: M=16384, N=3072, K=1024
  gemm8<M_QKV><<<dim3(12, 64, 1), dim3(512), 131072, stream>>>(
      xb, Wcat, Qb, Kb, Vt, bq, bk, bv, D, D, D, 0, 0);
  // Scores: per batch M=N=2048, K=1024
  gemm8<M_SC><<<dim3(8, 8, 8), dim3(512), 131072, stream>>>(
      Qb, Kb, Sbuf, nullptr, nullptr, nullptr, nullptr, nullptr,
      D, D, D, (size_t)S * D, (size_t)S * D);
  softmax2048_bf16<<<dim3((int)BS), dim3(256), 0, stream>>>(Sbuf);
  // PV: per batch M=2048, N=1024, K=2048; A=P (lda 4096), B=Vt (ldb 2048)
  gemm8<M_PV><<<dim3(4, 8, 8), dim3(512), 131072, stream>>>(
      (const unsigned short*)Sbuf, Vt, out, nullptr, nullptr, x, nullptr, nullptr,
      S, 2 * S, S, (size_t)S * 2 * S, (size_t)D * S);
  ln1024<<<dim3((int)BS), dim3(64), 0, stream>>>(out, gamma, beta);
}

// Round 7
// 494.103 us; speedup vs baseline: 5.9376x; 1.0493x over previous
//
#include <hip/hip_runtime.h>

// Self-attention block: bf16 MFMA GEMMs, 256x256/BK=64, 4-phase counted-vmcnt
// pipeline, fragment-contiguous LDS (0 bank conflicts, verified r5), with
// (r6) per-phase SPREAD staging issue + bijective XCD-aware block swizzle.
//   B=8, S=2048, D=1024
// GEMM: 512 thr = 8 waves in 2x4 (wave tile 128x64, acc[8][4] f32x4).
// LDS 128KB = 2 bufs x (A 32KB | B 32KB); each 16-row x 32-K fragment is a
// contiguous 1024B unit (unit*1024 + lane*16), written by global_load_lds
// with pre-permuted per-lane global source (linear LDS dest, rule #21).
// Per-wave stage order s0..s7 = [A-P0 ks0/1, B-P0 ks0/1, B-P1 ks0/1,
// A-P2 ks0/1]; tile tau+1's pairs issued at P0/P1/P2/P3 of tau (2 per phase,
// each pair lands 3 phases before its consumer's vmcnt). Ledger:
//   P0: vmcnt(4) always; P1: vmcnt(4|2 last); P2: vmcnt(4|0 last); P3: none.
// XCD swizzle: lin=(bx+gx*by); lin'=(lin&7)*(nwg/8)+(lin>>3) (nwg%8==0 all
// grids) -> each XCD gets a contiguous tile band (L2 panel reuse).
// ws (256MB): xb|Qb|Kb|Vt bf16 (128MB) + Sbuf f32 (128MB; Wcat bf16 in head).

typedef __bf16 bf16x8 __attribute__((ext_vector_type(8)));
typedef float f32x4 __attribute__((ext_vector_type(4)));

enum { M_QKV = 0, M_SC = 1, M_PV = 2 };

__device__ __forceinline__ unsigned short f2b(float f) {
  union { float f; unsigned int u; } v; v.f = f;
  return (unsigned short)((v.u + 0x7FFFu + ((v.u >> 16) & 1u)) >> 16);
}

#define GL16(gsrc, ldst)                                         \
  __builtin_amdgcn_global_load_lds(                              \
      (const __attribute__((address_space(1))) void*)(gsrc),     \
      (__attribute__((address_space(3))) void*)(ldst), 16, 0, 0)

template <int MODE>
__global__ __launch_bounds__(512, 2) void gemm8(
    const unsigned short* __restrict__ A, const unsigned short* __restrict__ B,
    void* __restrict__ C0, void* __restrict__ C1, void* __restrict__ C2,
    const float* __restrict__ x0, const float* __restrict__ x1,
    const float* __restrict__ x2,
    int K, int ldaE, int ldbE, size_t sA, size_t sB)
{
  extern __shared__ char lds[];
  const int t = threadIdx.x, l = t & 63, w = t >> 6;
  const int wm = w >> 2, wn = w & 3;          // 2x4 wave grid
  const int rl = l & 15, hi4 = l >> 4;
  const int cl8 = hi4 * 8;                    // k-elem offset within 32-block
  const int bz = blockIdx.z;
  const unsigned short* Ab = A + (size_t)bz * sA;
  const unsigned short* Bb = B + (size_t)bz * sB;

  // Bijective XCD-aware swizzle of the (x,y) tile coordinates (T1).
  const int nwg = gridDim.x * gridDim.y;      // 768 / 64 / 32 -> %8==0
  int lin = blockIdx.x + gridDim.x * blockIdx.y;
  lin = (lin & 7) * (nwg >> 3) + (lin >> 3);
  const int gm0 = (lin / gridDim.x) * 256, gn0 = (lin % gridDim.x) * 256;

  const int nt = K >> 6;

  // Per-wave staging assignment (units this wave writes each K-tile).
  const int frA0 = (w & 3) + (w >> 2) * 8;    // {0..3,8..11}: A mh0 set
  const int frB0 = (w >> 1) * 4 + (w & 1);    // {0,1,4,5,8,9,12,13}: B nh0 set

  const unsigned short* sp[8];
  int ub[8];
  sp[0] = Ab + (size_t)(gm0 + frA0 * 16 + rl) * ldaE + cl8;        // A-P0 ks0
  sp[1] = sp[0] + 32;                                              // A-P0 ks1
  sp[2] = Bb + (size_t)(gn0 + frB0 * 16 + rl) * ldbE + cl8;        // B-P0 ks0
  sp[3] = sp[2] + 32;
  sp[4] = Bb + (size_t)(gn0 + (frB0 + 2) * 16 + rl) * ldbE + cl8;  // B-P1 ks0
  sp[5] = sp[4] + 32;
  sp[6] = Ab + (size_t)(gm0 + (frA0 + 4) * 16 + rl) * ldaE + cl8;  // A-P2 ks0
  sp[7] = sp[6] + 32;
  ub[0] = frA0 * 2048;             ub[1] = ub[0] + 1024;
  ub[2] = 32768 + frB0 * 2048;     ub[3] = ub[2] + 1024;
  ub[4] = 32768 + (frB0 + 2) * 2048; ub[5] = ub[4] + 1024;
  ub[6] = (frA0 + 4) * 2048;       ub[7] = ub[6] + 1024;

  auto stage2 = [&](int tau, int buf, int s) {
    GL16(sp[s] + (size_t)tau * 64, lds + buf * 65536 + ub[s]);
    __builtin_amdgcn_sched_barrier(0);
    GL16(sp[s + 1] + (size_t)tau * 64, lds + buf * 65536 + ub[s + 1]);
    __builtin_amdgcn_sched_barrier(0);
  };

  f32x4 acc[8][4];
#pragma unroll
  for (int i = 0; i < 8; ++i)
#pragma unroll
    for (int j = 0; j < 4; ++j) acc[i][j] = f32x4{0.f, 0.f, 0.f, 0.f};

  // Prologue: all 8 units of tile 0 (FIFO order s0..s7).
  stage2(0, 0, 0); stage2(0, 0, 2); stage2(0, 0, 4); stage2(0, 0, 6);

  const int lb = l * 16;
  bf16x8 a[4][2], b0[2][2], b1[2][2];

  for (int tau = 0; tau < nt; ++tau) {
    const char* bp = lds + (tau & 1) * 65536;
    const int nb = (tau & 1) ^ 1;
    const bool more = (tau + 1) < nt;
    // -------- P0: quadrant (mh0, nh0) --------
    asm volatile("s_waitcnt vmcnt(4)" ::: "memory");
    __builtin_amdgcn_sched_barrier(0);
    __builtin_amdgcn_s_barrier();
    __builtin_amdgcn_sched_barrier(0);
    if (more) stage2(tau + 1, nb, 0);
#pragma unroll
    for (int mf = 0; mf < 4; ++mf)
#pragma unroll
      for (int ks = 0; ks < 2; ++ks)
        a[mf][ks] = *(const bf16x8*)(bp + ((wm * 8 + mf) * 2 + ks) * 1024 + lb);
#pragma unroll
    for (int nf = 0; nf < 2; ++nf)
#pragma unroll
      for (int ks = 0; ks < 2; ++ks)
        b0[nf][ks] = *(const bf16x8*)(bp + 32768 + ((wn * 4 + nf) * 2 + ks) * 1024 + lb);
    asm volatile("s_waitcnt lgkmcnt(0)" ::: "memory");
    __builtin_amdgcn_sched_barrier(0);
    __builtin_amdgcn_s_setprio(1);
#pragma unroll
    for (int mf = 0; mf < 4; ++mf)
#pragma unroll
      for (int nf = 0; nf < 2; ++nf)
#pragma unroll
        for (int ks = 0; ks < 2; ++ks)
          acc[mf][nf] = __builtin_amdgcn_mfma_f32_16x16x32_bf16(
              a[mf][ks], b0[nf][ks], acc[mf][nf], 0, 0, 0);
    __builtin_amdgcn_s_setprio(0);
    // -------- P1: (mh0, nh1) --------
    if (more) asm volatile("s_waitcnt vmcnt(4)" ::: "memory");
    else      asm volatile("s_waitcnt vmcnt(2)" ::: "memory");
    __builtin_amdgcn_sched_barrier(0);
    __builtin_amdgcn_s_barrier();
    __builtin_amdgcn_sched_barrier(0);
    if (more) stage2(tau + 1, nb, 2);
#pragma unroll
    for (int nf = 0; nf < 2; ++nf)
#pragma unroll
      for (int ks = 0; ks < 2; ++ks)
        b1[nf][ks] = *(const bf16x8*)(bp + 32768 + ((wn * 4 + 2 + nf) * 2 + ks) * 1024 + lb);
    asm volatile("s_waitcnt lgkmcnt(0)" ::: "memory");
    __builtin_amdgcn_sched_barrier(0);
    __builtin_amdgcn_s_setprio(1);
#pragma unroll
    for (int mf = 0; mf < 4; ++mf)
#pragma unroll
      for (int nf = 0; nf < 2; ++nf)
#pragma unroll
        for (int ks = 0; ks < 2; ++ks)
          acc[mf][2 + nf] = __builtin_amdgcn_mfma_f32_16x16x32_bf16(
              a[mf][ks], b1[nf][ks], acc[mf][2 + nf], 0, 0, 0);
    __builtin_amdgcn_s_setprio(0);
    // -------- P2: (mh1, nh1) --------
    if (more) asm volatile("s_waitcnt vmcnt(4)" ::: "memory");
    else      asm volatile("s_waitcnt vmcnt(0)" ::: "memory");
    __builtin_amdgcn_sched_barrier(0);
    __builtin_amdgcn_s_barrier();
    __builtin_amdgcn_sched_barrier(0);
    if (more) stage2(tau + 1, nb, 4);
#pragma unroll
    for (int mf = 0; mf < 4; ++mf)
#pragma unroll
      for (int ks = 0; ks < 2; ++ks)
        a[mf][ks] = *(const bf16x8*)(bp + ((wm * 8 + 4 + mf) * 2 + ks) * 1024 + lb);
    asm volatile("s_waitcnt lgkmcnt(0)" ::: "memory");
    __builtin_amdgcn_sched_barrier(0);
    __builtin_amdgcn_s_setprio(1);
#pragma unroll
    for (int mf = 0; mf < 4; ++mf)
#pragma unroll
      for (int nf = 0; nf < 2; ++nf)
#pragma unroll
        for (int ks = 0; ks < 2; ++ks)
          acc[4 + mf][2 + nf] = __builtin_amdgcn_mfma_f32_16x16x32_bf16(
              a[mf][ks], b1[nf][ks], acc[4 + mf][2 + nf], 0, 0, 0);
    __builtin_amdgcn_s_setprio(0);
    // -------- P3: (mh1, nh0) -- register-held operands, no wait/barrier ----
    if (more) stage2(tau + 1, nb, 6);
    __builtin_amdgcn_s_setprio(1);
#pragma unroll
    for (int mf = 0; mf < 4; ++mf)
#pragma unroll
      for (int nf = 0; nf < 2; ++nf)
#pragma unroll
        for (int ks = 0; ks < 2; ++ks)
          acc[4 + mf][nf] = __builtin_amdgcn_mfma_f32_16x16x32_bf16(
              a[mf][ks], b0[nf][ks], acc[4 + mf][nf], 0, 0, 0);
    __builtin_amdgcn_s_setprio(0);
  }

  // Epilogue. Frag (Mf,Nf): rows gm0+wm*128+Mf*16+hi4*4+r, col gn0+wn*64+Nf*16+rl.
#pragma unroll
  for (int Mf = 0; Mf < 8; ++Mf) {
    const int grow = gm0 + wm * 128 + Mf * 16 + hi4 * 4;
#pragma unroll
    for (int Nf = 0; Nf < 4; ++Nf) {
      const int gc = gn0 + wn * 64 + Nf * 16 + rl;
      if constexpr (MODE == M_QKV) {
        if (gc < 1024) {
          unsigned short* Q = (unsigned short*)C0;
          const float b = x0[gc];
#pragma unroll
          for (int r = 0; r < 4; ++r)
            Q[(size_t)(grow + r) * 1024 + gc] = f2b(acc[Mf][Nf][r] + b);
        } else if (gc < 2048) {
          unsigned short* Kk = (unsigned short*)C1;
          const float b = x1[gc - 1024];
#pragma unroll
          for (int r = 0; r < 4; ++r)
            Kk[(size_t)(grow + r) * 1024 + (gc - 1024)] = f2b(acc[Mf][Nf][r] + b);
        } else {
          unsigned short* Vt = (unsigned short*)C2;
          const float b = x2[gc - 2048];
          const int bat = grow >> 11, lm = grow & 2047;
          ushort4 o = make_ushort4(
              f2b(acc[Mf][Nf][0] + b), f2b(acc[Mf][Nf][1] + b),
              f2b(acc[Mf][Nf][2] + b), f2b(acc[Mf][Nf][3] + b));
          *(ushort4*)&Vt[(size_t)bat * 2097152 + (size_t)(gc - 2048) * 2048 + lm] = o;
        }
      } else if constexpr (MODE == M_SC) {
        float* C = (float*)C0 + (size_t)bz * 4194304;
        float* p = C + (size_t)grow * 2048 + gc;
#pragma unroll
        for (int r = 0; r < 4; ++r) p[(size_t)r * 2048] = acc[Mf][Nf][r] * 0.03125f;
      } else {  // M_PV
        float* C = (float*)C0 + (size_t)bz * 2097152;
        const float* R = x0 + (size_t)bz * 2097152;
        float* p = C + (size_t)grow * 1024 + gc;
        const float* q = R + (size_t)grow * 1024 + gc;
#pragma unroll
        for (int r = 0; r < 4; ++r) p[(size_t)r * 1024] = acc[Mf][Nf][r] + q[(size_t)r * 1024];
      }
    }
  }
}

__global__ __launch_bounds__(256) void f32_to_bf16(
    const float* __restrict__ s, unsigned short* __restrict__ d)
{
  const size_t i = (size_t)blockIdx.x * 256 + threadIdx.x;
  const float4 a = ((const float4*)s)[i * 2];
  const float4 b = ((const float4*)s)[i * 2 + 1];
  ((ushort4*)d)[i * 2]     = make_ushort4(f2b(a.x), f2b(a.y), f2b(a.z), f2b(a.w));
  ((ushort4*)d)[i * 2 + 1] = make_ushort4(f2b(b.x), f2b(b.y), f2b(b.z), f2b(b.w));
}

// Row softmax, fp32 in (row of 2048), bf16 out written in-place at row head.
__global__ __launch_bounds__(256) void softmax2048_bf16(float* __restrict__ S)
{
  __shared__ float redm[4];
  __shared__ float reds[4];
  const int t = threadIdx.x;
  float* p = S + (size_t)blockIdx.x * 2048;
  float4 a = *(const float4*)&p[t * 4];
  float4 b = *(const float4*)&p[t * 4 + 1024];
  float m = fmaxf(fmaxf(fmaxf(a.x, a.y), fmaxf(a.z, a.w)),
                  fmaxf(fmaxf(b.x, b.y), fmaxf(b.z, b.w)));
#pragma unroll
  for (int o = 32; o; o >>= 1) m = fmaxf(m, __shfl_xor(m, o));
  if ((t & 63) == 0) redm[t >> 6] = m;
  __syncthreads();
  m = fmaxf(fmaxf(redm[0], redm[1]), fmaxf(redm[2], redm[3]));
  a.x = __expf(a.x - m); a.y = __expf(a.y - m);
  a.z = __expf(a.z - m); a.w = __expf(a.w - m);
  b.x = __expf(b.x - m); b.y = __expf(b.y - m);
  b.z = __expf(b.z - m); b.w = __expf(b.w - m);
  float s = a.x + a.y + a.z + a.w + b.x + b.y + b.z + b.w;
#pragma unroll
  for (int o = 32; o; o >>= 1) s += __shfl_xor(s, o);
  if ((t & 63) == 0) reds[t >> 6] = s;
  __syncthreads();
  s = reds[0] + reds[1] + reds[2] + reds[3];
  const float inv = 1.0f / s;
  unsigned short* pb = (unsigned short*)p;
  *(ushort4*)&pb[t * 4] =
      make_ushort4(f2b(a.x * inv), f2b(a.y * inv), f2b(a.z * inv), f2b(a.w * inv));
  *(ushort4*)&pb[1024 + t * 4] =
      make_ushort4(f2b(b.x * inv), f2b(b.y * inv), f2b(b.z * inv), f2b(b.w * inv));
}

// In-place LayerNorm over D=1024, one wave per row.
__global__ __launch_bounds__(64) void ln1024(
    float* __restrict__ O, const float* __restrict__ g, const float* __restrict__ be)
{
  const int l = threadIdx.x;
  float* p = O + (size_t)blockIdx.x * 1024;
  float4 v[4];
#pragma unroll
  for (int i = 0; i < 4; ++i) v[i] = *(const float4*)&p[l * 4 + i * 256];
  float s = 0.f, q = 0.f;
#pragma unroll
  for (int i = 0; i < 4; ++i) {
    s += v[i].x + v[i].y + v[i].z + v[i].w;
    q += v[i].x * v[i].x + v[i].y * v[i].y + v[i].z * v[i].z + v[i].w * v[i].w;
  }
#pragma unroll
  for (int o = 32; o; o >>= 1) { s += __shfl_xor(s, o); q += __shfl_xor(q, o); }
  const float mu = s * (1.0f / 1024.0f);
  const float var = q * (1.0f / 1024.0f) - mu * mu;
  const float rs = rsqrtf(var + 1e-5f);
#pragma unroll
  for (int i = 0; i < 4; ++i) {
    const float4 gg = *(const float4*)&g[l * 4 + i * 256];
    const float4 bb = *(const float4*)&be[l * 4 + i * 256];
    float4 o4;
    o4.x = (v[i].x - mu) * rs * gg.x + bb.x;
    o4.y = (v[i].y - mu) * rs * gg.y + bb.y;
    o4.z = (v[i].z - mu) * rs * gg.z + bb.z;
    o4.w = (v[i].w - mu) * rs * gg.w + bb.w;
    *(float4*)&p[l * 4 + i * 256] = o4;
  }
}

extern "C" void kernel_launch(void* const* d_in, const int* in_sizes, int n_in,
                              void* d_out, int out_size, void* d_ws, size_t ws_size,
                              hipStream_t stream) {
  (void)in_sizes; (void)n_in; (void)out_size; (void)ws_size;
  constexpr int Bb = 8, S = 2048, D = 1024;
  const size_t BS = (size_t)Bb * S;
  const size_t ND = BS * (size_t)D;

  const float* x     = (const float*)d_in[0];
  const float* Wq    = (const float*)d_in[1];
  const float* bq    = (const float*)d_in[2];
  const float* Wk    = (const float*)d_in[3];
  const float* bk    = (const float*)d_in[4];
  const float* Wv    = (const float*)d_in[5];
  const float* bv    = (const float*)d_in[6];
  const float* gamma = (const float*)d_in[7];
  const float* beta  = (const float*)d_in[8];
  float* out = (float*)d_out;

  unsigned short* xb = (unsigned short*)d_ws;
  unsigned short* Qb = xb + ND;
  unsigned short* Kb = Qb + ND;
  unsigned short* Vt = Kb + ND;
  float* Sbuf = (float*)(Vt + ND);
  unsigned short* Wcat = (unsigned short*)Sbuf;  // [3072][1024], dead by scores

  hipFuncSetAttribute((const void*)gemm8<M_QKV>,
                      hipFuncAttributeMaxDynamicSharedMemorySize, 131072);
  hipFuncSetAttribute((const void*)gemm8<M_SC>,
                      hipFuncAttributeMaxDynamicSharedMemorySize, 131072);
  hipFuncSetAttribute((const void*)gemm8<M_PV>,
                      hipFuncAttributeMaxDynamicSharedMemorySize, 131072);

  f32_to_bf16<<<dim3(8192), dim3(256), 0, stream>>>(x, xb);
  f32_to_bf16<<<dim3(512), dim3(256), 0, stream>>>(Wq, Wcat);
  f32_to_bf16<<<dim3(512), dim3(256), 0, stream>>>(Wk, Wcat + (size_t)D * D);
  f32_to_bf16<<<dim3(512), dim3(256), 0, stream>>>(Wv, Wcat + 2 * (size_t)D * D);

  // Fused QKV: M=16384, N=3072, K=1024
  gemm8<M_QKV><<<dim3(12, 64, 1), dim3(512), 131072, stream>>>(
      xb, Wcat, Qb, Kb, Vt, bq, bk, bv, D, D, D, 0, 0);
  // Scores: per batch M=N=2048, K=1024
  gemm8<M_SC><<<dim3(8, 8, 8), dim3(512), 131072, stream>>>(
      Qb, Kb, Sbuf, nullptr, nullptr, nullptr, nullptr, nullptr,
      D, D, D, (size_t)S * D, (size_t)S * D);
  softmax2048_bf16<<<dim3((int)BS), dim3(256), 0, stream>>>(Sbuf);
  // PV: per batch M=2048, N=1024, K=2048; A=P (lda 4096), B=Vt (ldb 2048)
  gemm8<M_PV><<<dim3(4, 8, 8), dim3(512), 131072, stream>>>(
      (const unsigned short*)Sbuf, Vt, out, nullptr, nullptr, x, nullptr, nullptr,
      S, 2 * S, S, (size_t)S * 2 * S, (size_t)D * S);
  ln1024<<<dim3((int)BS), dim3(64), 0, stream>>>(out, gamma, beta);
}